// Round 4
// baseline (427.315 us; speedup 1.0000x reference)
//
#include <hip/hip_runtime.h>

#define ROWP 108   // LDS row stride in floats: 108%32=12 -> b128 lane windows tile all banks; 16B aligned

// ws layout (floats):
//  h2   [0        , 3276800)   32768 rows
//  h5   [3276800  , 3686400)    4096 rows
//  h8   [3686400  , 3737600)     512 rows
//  h11  [3737600  , 3744000)      64 rows
//  WlTa [3744000  , 3755200)   100 x 112: WlTa[e*112 + w*28 + o] = Wl[(w*25+o)*100 + e], pad o>=25 -> 0

__global__ void prep_kernel(const float* __restrict__ Wl, float* __restrict__ WlTa) {
  int i = blockIdx.x * 256 + threadIdx.x;
  if (i < 11200) {
    int e = i / 112, c = i % 112;
    int w = c / 28, o = c % 28;
    WlTa[i] = (o < 25) ? Wl[(w * 25 + o) * 100 + e] : 0.0f;
  }
}

__device__ __forceinline__ void fma28(float* acc, float sv, const float4* w4) {
  #pragma unroll
  for (int q = 0; q < 7; ++q) {
    float4 w = w4[q];
    acc[4*q+0] = fmaf(sv, w.x, acc[4*q+0]);
    acc[4*q+1] = fmaf(sv, w.y, acc[4*q+1]);
    acc[4*q+2] = fmaf(sv, w.z, acc[4*q+2]);
    acc[4*q+3] = fmaf(sv, w.w, acc[4*q+3]);
  }
}

// One tree level: n nodes (pow2 <= 64) from summed child rows S (LDS).
// wave -> out-chunk [wave*25,+25); lane: node = lane&(n-1), rep = lane>>ln splits e-range.
// Writes relu'd rows into H (LDS) and projection partials into PJ. Caller barriers.
__device__ __forceinline__ void level_compute(
    const float* S, float* H, float (*PJ)[64][2],
    const float* __restrict__ WlTa, const float* __restrict__ bl,
    const float* __restrict__ Wp, int lane, int wave, int n, int ln) {
  int reps = 64 >> ln; if (reps > 4) reps = 4;
  int node = lane & (n - 1);
  int rep  = lane >> ln;
  int obase = wave * 25, wbase = wave * 28;
  float acc[28];
  #pragma unroll
  for (int o = 0; o < 28; ++o) acc[o] = 0.0f;
  if (rep == 0) {
    #pragma unroll
    for (int o = 0; o < 25; ++o) acc[o] = 2.0f * bl[obase + o];
  }
  if (rep < reps) {
    int ec0 = (rep * 25) / reps, ec1 = ((rep + 1) * 25) / reps;
    const float4* s4 = (const float4*)(S + node * ROWP);
    for (int ec = ec0; ec < ec1; ++ec) {
      float4 sv = s4[ec];
      const float4* w0 = (const float4*)(WlTa + (4*ec+0)*112 + wbase);  // uniform -> s_load
      const float4* w1 = (const float4*)(WlTa + (4*ec+1)*112 + wbase);
      const float4* w2 = (const float4*)(WlTa + (4*ec+2)*112 + wbase);
      const float4* w3 = (const float4*)(WlTa + (4*ec+3)*112 + wbase);
      fma28(acc, sv.x, w0);
      fma28(acc, sv.y, w1);
      fma28(acc, sv.z, w2);
      fma28(acc, sv.w, w3);
    }
  }
  for (int m = (n * reps) >> 1; m >= n; m >>= 1) {
    #pragma unroll
    for (int o = 0; o < 25; ++o) acc[o] += __shfl_xor(acc[o], m, 64);
  }
  if (rep == 0) {
    float pj0 = 0.f, pj1 = 0.f;
    #pragma unroll
    for (int o = 0; o < 25; ++o) {
      float v = fmaxf(acc[o], 0.f);
      H[node * ROWP + obase + o] = v;
      pj0 = fmaf(v, Wp[obase + o], pj0);
      pj1 = fmaf(v, Wp[100 + obase + o], pj1);
    }
    PJ[wave][node][0] = pj0;
    PJ[wave][node][1] = pj1;
  }
}

// ---------------------------------------------------------------------------
// Leaf kernel: 64 leaves/block -> leaf proj (lvl0) + levels 1,2; writes h2 (16 rows).
// ---------------------------------------------------------------------------
__global__ __launch_bounds__(256) void leaf_kernel(
    const int* __restrict__ word_ids, const float* __restrict__ emb,
    const float* __restrict__ WlTa, const float* __restrict__ bl,
    const float* __restrict__ Wp, const float* __restrict__ bp,
    float* __restrict__ hdst, float* __restrict__ out) {
  __shared__ float L[64 * ROWP];
  __shared__ float S[32 * ROWP];
  __shared__ float H[32 * ROWP];
  __shared__ float PJ[4][64][2];
  __shared__ float PJL[4][64][2];
  const int tid = threadIdx.x, lane = tid & 63;
  const int wave = __builtin_amdgcn_readfirstlane(tid >> 6);
  const int blk = blockIdx.x;

  // gather 64 leaf rows (coalesced 400B bursts)
  for (int i = tid; i < 64 * 25; i += 256) {
    int lf = i / 25, q = i % 25;
    int w = word_ids[blk * 64 + lf];
    *(float4*)(L + lf * ROWP + q * 4) = ((const float4*)(emb + (size_t)w * 100))[q];
  }
  __syncthreads();

  // leaf projections: lane = leaf, wave splits e-range
  {
    int ec0 = (wave * 25) / 4, ec1 = ((wave + 1) * 25) / 4;
    const float4* r4  = (const float4*)(L + lane * ROWP);
    const float4* wp0 = (const float4*)Wp;
    const float4* wp1 = (const float4*)(Wp + 100);
    float p0 = 0.f, p1 = 0.f;
    for (int ec = ec0; ec < ec1; ++ec) {
      float4 x = r4[ec];
      float4 a = wp0[ec], b = wp1[ec];
      p0 = fmaf(x.x,a.x,p0); p0 = fmaf(x.y,a.y,p0); p0 = fmaf(x.z,a.z,p0); p0 = fmaf(x.w,a.w,p0);
      p1 = fmaf(x.x,b.x,p1); p1 = fmaf(x.y,b.y,p1); p1 = fmaf(x.z,b.z,p1); p1 = fmaf(x.w,b.w,p1);
    }
    PJL[wave][lane][0] = p0; PJL[wave][lane][1] = p1;
  }
  // pairsum leaves -> S (32 rows)
  for (int i = tid; i < 32 * 25; i += 256) {
    int nd = i / 25, q = i % 25;
    float4 a = *(const float4*)(L + (2*nd)   * ROWP + q * 4);
    float4 b = *(const float4*)(L + (2*nd+1) * ROWP + q * 4);
    float4 s; s.x=a.x+b.x; s.y=a.y+b.y; s.z=a.z+b.z; s.w=a.w+b.w;
    *(float4*)(S + nd * ROWP + q * 4) = s;
  }
  __syncthreads();

  // leaf (level-0) out
  if (tid < 64) {
    float p0 = PJL[0][tid][0]+PJL[1][tid][0]+PJL[2][tid][0]+PJL[3][tid][0] + bp[0];
    float p1 = PJL[0][tid][1]+PJL[1][tid][1]+PJL[2][tid][1]+PJL[3][tid][1] + bp[1];
    long g = (long)blk * 64 + tid;
    long pos = ((g + 1) << 1) - 2 - __popc((unsigned)g);
    out[2*pos] = p0; out[2*pos+1] = p1;
  }

  // levels 1,2
  int n = 32, ln = 5;
  for (int j = 0; j < 2; ++j, n >>= 1, --ln) {
    level_compute(S, H, PJ, WlTa, bl, Wp, lane, wave, n, ln);
    __syncthreads();
    if (tid < n) {
      float p0 = PJ[0][tid][0]+PJ[1][tid][0]+PJ[2][tid][0]+PJ[3][tid][0] + bp[0];
      float p1 = PJ[0][tid][1]+PJ[1][tid][1]+PJ[2][tid][1]+PJ[3][tid][1] + bp[1];
      long g = (long)blk * n + tid;
      int lvl = 1 + j;
      long pos = ((g + 1) << (lvl + 1)) - 2 - __popc((unsigned)g);
      out[2*pos] = p0; out[2*pos+1] = p1;
    }
    if (j == 0) {
      for (int i = tid; i < 16 * 25; i += 256) {
        int nd = i / 25, q = i % 25;
        float4 a = *(const float4*)(H + (2*nd)   * ROWP + q * 4);
        float4 b = *(const float4*)(H + (2*nd+1) * ROWP + q * 4);
        float4 s; s.x=a.x+b.x; s.y=a.y+b.y; s.z=a.z+b.z; s.w=a.w+b.w;
        *(float4*)(S + nd * ROWP + q * 4) = s;
      }
    }
    __syncthreads();
  }

  // write h2: 16 rows, coalesced float4
  float4* dst4 = (float4*)hdst + (size_t)blk * 16 * 25;
  for (int i = tid; i < 16 * 25; i += 256)
    dst4[i] = *(const float4*)(H + (i/25)*ROWP + (i%25)*4);
}

// ---------------------------------------------------------------------------
// Generic multi-level kernel: block takes n0 nodes at startLvl (reads 2*n0 child
// rows from hsrc), runs nLvl levels internally, optionally writes last rows.
// ---------------------------------------------------------------------------
__global__ __launch_bounds__(256) void tree_kernel(
    const float* __restrict__ hsrc, float* __restrict__ hdst,
    const float* __restrict__ WlTa, const float* __restrict__ bl,
    const float* __restrict__ Wp, const float* __restrict__ bp,
    float* __restrict__ out, int startLvl, int nLvl, int ln0, int wantH) {
  __shared__ float S[64 * ROWP];
  __shared__ float H[64 * ROWP];
  __shared__ float PJ[4][64][2];
  const int tid = threadIdx.x, lane = tid & 63;
  const int wave = __builtin_amdgcn_readfirstlane(tid >> 6);
  const int blk = blockIdx.x;
  const int n0 = 1 << ln0;

  // stage + pairsum children from global (coalesced float4)
  const float4* src4 = (const float4*)hsrc + (size_t)blk * n0 * 50;
  for (int i = tid; i < n0 * 25; i += 256) {
    int nd = i / 25, q = i % 25;
    float4 a = src4[nd * 50 + q];
    float4 b = src4[nd * 50 + 25 + q];
    float4 s; s.x=a.x+b.x; s.y=a.y+b.y; s.z=a.z+b.z; s.w=a.w+b.w;
    *(float4*)(S + nd * ROWP + q * 4) = s;
  }
  __syncthreads();

  int n = n0, ln = ln0;
  for (int j = 0; j < nLvl; ++j, n >>= 1, --ln) {
    level_compute(S, H, PJ, WlTa, bl, Wp, lane, wave, n, ln);
    __syncthreads();
    if (tid < n) {
      float p0 = PJ[0][tid][0]+PJ[1][tid][0]+PJ[2][tid][0]+PJ[3][tid][0] + bp[0];
      float p1 = PJ[0][tid][1]+PJ[1][tid][1]+PJ[2][tid][1]+PJ[3][tid][1] + bp[1];
      long g = (long)blk * n + tid;
      int lvl = startLvl + j;
      long pos = ((g + 1) << (lvl + 1)) - 2 - __popc((unsigned)g);
      out[2*pos] = p0; out[2*pos+1] = p1;
    }
    if (j + 1 < nLvl) {
      int nn = n >> 1;
      for (int i = tid; i < nn * 25; i += 256) {
        int nd = i / 25, q = i % 25;
        float4 a = *(const float4*)(H + (2*nd)   * ROWP + q * 4);
        float4 b = *(const float4*)(H + (2*nd+1) * ROWP + q * 4);
        float4 s; s.x=a.x+b.x; s.y=a.y+b.y; s.z=a.z+b.z; s.w=a.w+b.w;
        *(float4*)(S + nd * ROWP + q * 4) = s;
      }
    }
    __syncthreads();
  }

  if (wantH) {
    int R = n0 >> (nLvl - 1);
    float4* dst4 = (float4*)hdst + (size_t)blk * R * 25;
    for (int i = tid; i < R * 25; i += 256)
      dst4[i] = *(const float4*)(H + (i/25)*ROWP + (i%25)*4);
  }
}

extern "C" void kernel_launch(void* const* d_in, const int* in_sizes, int n_in,
                              void* d_out, int out_size, void* d_ws, size_t ws_size,
                              hipStream_t stream) {
  const int*   word_ids = (const int*)  d_in[0];
  const float* emb      = (const float*)d_in[1];
  const float* Wl       = (const float*)d_in[2];
  const float* bl       = (const float*)d_in[3];
  const float* Wp       = (const float*)d_in[4];
  const float* bp       = (const float*)d_in[5];
  float* out = (float*)d_out;

  float* ws   = (float*)d_ws;
  float* h2   = ws;
  float* h5   = ws + 3276800;
  float* h8   = ws + 3686400;
  float* h11  = ws + 3737600;
  float* WlTa = ws + 3744000;

  prep_kernel<<<44, 256, 0, stream>>>(Wl, WlTa);

  // lvls 0,1,2: 2048 blocks x 64 leaves
  leaf_kernel<<<2048, 256, 0, stream>>>(word_ids, emb, WlTa, bl, Wp, bp, h2, out);

  // lvls 3,4,5: 256 blocks x 64 lvl-3 nodes (reads h2), writes h5
  tree_kernel<<<256, 256, 0, stream>>>(h2, h5, WlTa, bl, Wp, bp, out, 3, 3, 6, 1);
  // lvls 6,7,8: 32 blocks, writes h8
  tree_kernel<<<32, 256, 0, stream>>>(h5, h8, WlTa, bl, Wp, bp, out, 6, 3, 6, 1);
  // lvls 9,10,11: 4 blocks, writes h11
  tree_kernel<<<4, 256, 0, stream>>>(h8, h11, WlTa, bl, Wp, bp, out, 9, 3, 6, 1);
  // lvls 12..17: 1 block, n0=32 (reads 64 rows of h11), no h output
  tree_kernel<<<1, 256, 0, stream>>>(h11, nullptr, WlTa, bl, Wp, bp, out, 12, 6, 5, 0);
}

// Round 5
// 207.081 us; speedup vs baseline: 2.0635x; 2.0635x over previous
//
#include <hip/hip_runtime.h>

#define RW 50   // row stride in dwords (50 f16-pairs = 100 values)

typedef _Float16 h2v __attribute__((ext_vector_type(2)));

__device__ __forceinline__ unsigned pk2(float a, float b) {
  unsigned short ha = __builtin_bit_cast(unsigned short, (_Float16)a);
  unsigned short hb = __builtin_bit_cast(unsigned short, (_Float16)b);
  return (unsigned)ha | ((unsigned)hb << 16);
}
__device__ __forceinline__ float2 upk(unsigned u) {
  _Float16 lo = __builtin_bit_cast(_Float16, (unsigned short)(u & 0xffffu));
  _Float16 hi = __builtin_bit_cast(_Float16, (unsigned short)(u >> 16));
  return make_float2((float)lo, (float)hi);
}
__device__ __forceinline__ float dot2u(unsigned s, unsigned w, float c) {
#if __has_builtin(__builtin_amdgcn_fdot2)
  return __builtin_amdgcn_fdot2(__builtin_bit_cast(h2v, s),
                                __builtin_bit_cast(h2v, w), c, false);
#else
  float2 a = upk(s), b = upk(w);
  return fmaf(a.x, b.x, fmaf(a.y, b.y, c));
#endif
}

// Wpk[p*112 + w*28 + o] = pack(Wl[ob][2p], Wl[ob][2p+1]), ob = w*26+o, o<C(w) else 0
// C(w) = 26,26,26,22 ; p = 0..49 input e-pairs
__global__ void prep_kernel(const float* __restrict__ Wl, unsigned* __restrict__ Wpk) {
  int i = blockIdx.x * 256 + threadIdx.x;
  if (i < 5600) {
    int p = i / 112, c = i % 112, w = c / 28, o = c % 28;
    int C = (w < 3) ? 26 : 22;
    unsigned v = 0;
    if (o < C) {
      int ob = w * 26 + o;
      v = pk2(Wl[ob * 100 + 2 * p], Wl[ob * 100 + 2 * p + 1]);
    }
    Wpk[i] = v;
  }
}

// One level: n output nodes from A (n summed-child rows, f16 pairs), writes
// relu'd rows to B and projection partials to PJ. Caller barriers afterwards.
__device__ __forceinline__ void level_f16(
    const unsigned* __restrict__ A, unsigned* __restrict__ B,
    float (* __restrict__ PJ)[128][2], const unsigned* __restrict__ Wlds,
    const float* __restrict__ bl, const float* __restrict__ Wp,
    int lane, int wave, int n, int ln) {
  const int obase = wave * 26;
  const int Cw = (wave < 3) ? 26 : 22;
  const bool two = (n == 128);
  int node = lane, rep = 0, reps = 1, p0 = 0, p1 = 50;
  if (n < 64) {
    reps = 64 >> ln; if (reps > 4) reps = 4;
    node = lane & (n - 1);
    rep  = lane >> ln;
    if (rep < reps) { p0 = (rep * 50) / reps; p1 = ((rep + 1) * 50) / reps; }
    else            { p0 = 0; p1 = 0; }
  }
  float acc[28], acc2[28];
  #pragma unroll
  for (int o = 0; o < 28; ++o) { acc[o] = 0.f; acc2[o] = 0.f; }
  if (rep == 0) {
    #pragma unroll
    for (int o = 0; o < 28; ++o) if (o < Cw) {
      float b2 = 2.0f * bl[obase + o];
      acc[o] = b2; acc2[o] = b2;
    }
  }
  const unsigned* r1 = A + node * RW;
  const unsigned* wb = Wlds + wave * 28;
  if (two) {
    const unsigned* r2 = A + (node + 64) * RW;
    #pragma unroll 2
    for (int p = 0; p < 50; ++p) {
      unsigned s1 = r1[p], s2 = r2[p];
      const uint4* w4 = (const uint4*)(wb + p * 112);
      #pragma unroll
      for (int j = 0; j < 7; ++j) {
        uint4 w = w4[j];
        acc[4*j+0]  = dot2u(s1, w.x, acc[4*j+0]);
        acc[4*j+1]  = dot2u(s1, w.y, acc[4*j+1]);
        acc[4*j+2]  = dot2u(s1, w.z, acc[4*j+2]);
        acc[4*j+3]  = dot2u(s1, w.w, acc[4*j+3]);
        acc2[4*j+0] = dot2u(s2, w.x, acc2[4*j+0]);
        acc2[4*j+1] = dot2u(s2, w.y, acc2[4*j+1]);
        acc2[4*j+2] = dot2u(s2, w.z, acc2[4*j+2]);
        acc2[4*j+3] = dot2u(s2, w.w, acc2[4*j+3]);
      }
    }
  } else {
    #pragma unroll 2
    for (int p = p0; p < p1; ++p) {
      unsigned s1 = r1[p];
      const uint4* w4 = (const uint4*)(wb + p * 112);
      #pragma unroll
      for (int j = 0; j < 7; ++j) {
        uint4 w = w4[j];
        acc[4*j+0] = dot2u(s1, w.x, acc[4*j+0]);
        acc[4*j+1] = dot2u(s1, w.y, acc[4*j+1]);
        acc[4*j+2] = dot2u(s1, w.z, acc[4*j+2]);
        acc[4*j+3] = dot2u(s1, w.w, acc[4*j+3]);
      }
    }
    if (n < 64) {
      for (int m = (n * reps) >> 1; m >= n; m >>= 1) {
        #pragma unroll
        for (int o = 0; o < 26; ++o) acc[o] += __shfl_xor(acc[o], m, 64);
      }
    }
  }
  if (rep == 0) {
    float pj0 = 0.f, pj1 = 0.f;
    unsigned* hrow = B + node * RW + wave * 13;
    #pragma unroll
    for (int k = 0; k < 13; ++k) if (2 * k < Cw) {
      float v0 = fmaxf(acc[2*k],   0.f);
      float v1 = fmaxf(acc[2*k+1], 0.f);
      hrow[k] = pk2(v0, v1);
      pj0 = fmaf(v0, Wp[obase + 2*k],       fmaf(v1, Wp[obase + 2*k + 1],       pj0));
      pj1 = fmaf(v0, Wp[100 + obase + 2*k], fmaf(v1, Wp[100 + obase + 2*k + 1], pj1));
    }
    PJ[wave][node][0] = pj0; PJ[wave][node][1] = pj1;
    if (two) {
      float q0 = 0.f, q1 = 0.f;
      unsigned* hrow2 = B + (node + 64) * RW + wave * 13;
      #pragma unroll
      for (int k = 0; k < 13; ++k) if (2 * k < Cw) {
        float v0 = fmaxf(acc2[2*k],   0.f);
        float v1 = fmaxf(acc2[2*k+1], 0.f);
        hrow2[k] = pk2(v0, v1);
        q0 = fmaf(v0, Wp[obase + 2*k],       fmaf(v1, Wp[obase + 2*k + 1],       q0));
        q1 = fmaf(v0, Wp[100 + obase + 2*k], fmaf(v1, Wp[100 + obase + 2*k + 1], q1));
      }
      PJ[wave][node + 64][0] = q0; PJ[wave][node + 64][1] = q1;
    }
  }
}

// Leaf kernel: 256 leaves/block -> lvl0 proj + levels 1,2,3; writes 32 h3 rows.
__global__ __launch_bounds__(256) void leaf_kernel(
    const int* __restrict__ word_ids, const float* __restrict__ emb,
    const unsigned* __restrict__ Wpk, const float* __restrict__ bl,
    const float* __restrict__ Wp, const float* __restrict__ bp,
    unsigned* __restrict__ h3, float* __restrict__ out) {
  __shared__ unsigned A[128 * RW];
  __shared__ unsigned B[128 * RW];
  __shared__ unsigned Wlds[5600];
  __shared__ float PJ[4][128][2];
  __shared__ int wid[256];
  const int tid = threadIdx.x, lane = tid & 63;
  const int wave = __builtin_amdgcn_readfirstlane(tid >> 6);
  const int blk = blockIdx.x;

  wid[tid] = word_ids[blk * 256 + tid];
  for (int i = tid; i < 1400; i += 256) ((uint4*)Wlds)[i] = ((const uint4*)Wpk)[i];
  __syncthreads();

  // phase A: full leaf row in registers
  float r[100];
  {
    const float4* row4 = (const float4*)(emb + (size_t)wid[tid] * 100);
    #pragma unroll
    for (int q = 0; q < 25; ++q) {
      float4 v = row4[q];
      r[4*q] = v.x; r[4*q+1] = v.y; r[4*q+2] = v.z; r[4*q+3] = v.w;
    }
  }
  // leaf projection (fp32, exact inputs)
  {
    const float4* wp0 = (const float4*)Wp;
    const float4* wp1 = (const float4*)(Wp + 100);
    float p0 = bp[0], p1 = bp[1];
    #pragma unroll
    for (int q = 0; q < 25; ++q) {
      float4 a = wp0[q], b = wp1[q];
      p0 = fmaf(r[4*q],a.x,p0); p0 = fmaf(r[4*q+1],a.y,p0);
      p0 = fmaf(r[4*q+2],a.z,p0); p0 = fmaf(r[4*q+3],a.w,p0);
      p1 = fmaf(r[4*q],b.x,p1); p1 = fmaf(r[4*q+1],b.y,p1);
      p1 = fmaf(r[4*q+2],b.z,p1); p1 = fmaf(r[4*q+3],b.w,p1);
    }
    int g = blk * 256 + tid;
    long pos = 2L * g - __popc((unsigned)g);
    out[2*pos] = p0; out[2*pos+1] = p1;
  }
  // pair-sum via shuffle -> A rows (f16 packed)
  #pragma unroll
  for (int d = 0; d < 50; ++d) {
    float s0 = r[2*d]   + __shfl_xor(r[2*d],   1, 64);
    float s1 = r[2*d+1] + __shfl_xor(r[2*d+1], 1, 64);
    if ((tid & 1) == 0) A[(tid >> 1) * RW + d] = pk2(s0, s1);
  }
  __syncthreads();

  int n = 128;
  for (int j = 0; j < 3; ++j) {
    level_f16(A, B, PJ, Wlds, bl, Wp, lane, wave, n, 7 - j);
    __syncthreads();
    if (tid < n) {
      float p0 = PJ[0][tid][0]+PJ[1][tid][0]+PJ[2][tid][0]+PJ[3][tid][0] + bp[0];
      float p1 = PJ[0][tid][1]+PJ[1][tid][1]+PJ[2][tid][1]+PJ[3][tid][1] + bp[1];
      int g = blk * n + tid, lvl = 1 + j;
      long pos = (((long)g + 1) << (lvl + 1)) - 2 - __popc((unsigned)g);
      out[2*pos] = p0; out[2*pos+1] = p1;
    }
    if (j < 2) {
      int nn = n >> 1;
      for (int i = tid; i < nn * RW; i += 256) {
        int nd = i / RW, d = i % RW;
        float2 x = upk(B[(2*nd) * RW + d]);
        float2 y = upk(B[(2*nd+1) * RW + d]);
        A[nd * RW + d] = pk2(x.x + y.x, x.y + y.y);
      }
    }
    __syncthreads();
    n >>= 1;
  }
  for (int i = tid; i < 32 * RW; i += 256) h3[(size_t)blk * 32 * RW + i] = B[i];
}

// Generic multi-level tree kernel.
__global__ __launch_bounds__(256) void tree_kernel(
    const unsigned* __restrict__ hsrc, unsigned* __restrict__ hdst,
    const unsigned* __restrict__ Wpk, const float* __restrict__ bl,
    const float* __restrict__ Wp, const float* __restrict__ bp,
    float* __restrict__ out, int startLvl, int nLvl, int n0, int ln0, int wantH) {
  __shared__ unsigned A[128 * RW];
  __shared__ unsigned B[128 * RW];
  __shared__ unsigned Wlds[5600];
  __shared__ float PJ[4][128][2];
  const int tid = threadIdx.x, lane = tid & 63;
  const int wave = __builtin_amdgcn_readfirstlane(tid >> 6);
  const int blk = blockIdx.x;

  for (int i = tid; i < 1400; i += 256) ((uint4*)Wlds)[i] = ((const uint4*)Wpk)[i];
  const unsigned* src = hsrc + (size_t)blk * (2 * n0) * RW;
  for (int i = tid; i < n0 * RW; i += 256) {
    int nd = i / RW, d = i % RW;
    float2 x = upk(src[(2*nd) * RW + d]);
    float2 y = upk(src[(2*nd+1) * RW + d]);
    A[nd * RW + d] = pk2(x.x + y.x, x.y + y.y);
  }
  __syncthreads();

  int n = n0, ln = ln0;
  for (int j = 0; j < nLvl; ++j) {
    level_f16(A, B, PJ, Wlds, bl, Wp, lane, wave, n, ln);
    __syncthreads();
    if (tid < n) {
      float p0 = PJ[0][tid][0]+PJ[1][tid][0]+PJ[2][tid][0]+PJ[3][tid][0] + bp[0];
      float p1 = PJ[0][tid][1]+PJ[1][tid][1]+PJ[2][tid][1]+PJ[3][tid][1] + bp[1];
      int g = blk * n + tid, lvl = startLvl + j;
      long pos = (((long)g + 1) << (lvl + 1)) - 2 - __popc((unsigned)g);
      out[2*pos] = p0; out[2*pos+1] = p1;
    }
    if (j + 1 < nLvl) {
      int nn = n >> 1;
      for (int i = tid; i < nn * RW; i += 256) {
        int nd = i / RW, d = i % RW;
        float2 x = upk(B[(2*nd) * RW + d]);
        float2 y = upk(B[(2*nd+1) * RW + d]);
        A[nd * RW + d] = pk2(x.x + y.x, x.y + y.y);
      }
    }
    __syncthreads();
    n >>= 1; --ln;
  }
  if (wantH) {
    int R = n0 >> (nLvl - 1);
    for (int i = tid; i < R * RW; i += 256) hdst[(size_t)blk * R * RW + i] = B[i];
  }
}

extern "C" void kernel_launch(void* const* d_in, const int* in_sizes, int n_in,
                              void* d_out, int out_size, void* d_ws, size_t ws_size,
                              hipStream_t stream) {
  const int*   word_ids = (const int*)  d_in[0];
  const float* emb      = (const float*)d_in[1];
  const float* Wl       = (const float*)d_in[2];
  const float* bl       = (const float*)d_in[3];
  const float* Wp       = (const float*)d_in[4];
  const float* bp       = (const float*)d_in[5];
  float* out = (float*)d_out;

  unsigned* ws  = (unsigned*)d_ws;
  unsigned* h3  = ws;                 // 16384 rows
  unsigned* h5  = ws + 819200;        //  4096 rows
  unsigned* h7  = ws + 1024000;       //  1024 rows
  unsigned* h9  = ws + 1075200;       //   256 rows
  unsigned* h13 = ws + 1088000;       //    16 rows
  unsigned* Wpk = ws + 1088800;       //  5600 dwords

  prep_kernel<<<22, 256, 0, stream>>>(Wl, Wpk);
  // lvls 0-3
  leaf_kernel<<<512, 256, 0, stream>>>(word_ids, emb, Wpk, bl, Wp, bp, h3, out);
  // lvls 4,5 : 128 blocks x n0=64
  tree_kernel<<<128, 256, 0, stream>>>(h3, h5, Wpk, bl, Wp, bp, out, 4, 2, 64, 6, 1);
  // lvls 6,7 : 32 blocks
  tree_kernel<<<32, 256, 0, stream>>>(h5, h7, Wpk, bl, Wp, bp, out, 6, 2, 64, 6, 1);
  // lvls 8,9 : 8 blocks
  tree_kernel<<<8, 256, 0, stream>>>(h7, h9, Wpk, bl, Wp, bp, out, 8, 2, 64, 6, 1);
  // lvls 10-13 : 4 blocks x n0=32
  tree_kernel<<<4, 256, 0, stream>>>(h9, h13, Wpk, bl, Wp, bp, out, 10, 4, 32, 5, 1);
  // lvls 14-17 : 1 block x n0=8
  tree_kernel<<<1, 256, 0, stream>>>(h13, nullptr, Wpk, bl, Wp, bp, out, 14, 4, 8, 3, 0);
}